// Round 2
// baseline (802.226 us; speedup 1.0000x reference)
//
#include <hip/hip_runtime.h>
#include <hip/hip_bf16.h>

#define N_NODES 50000

// ---------------------------------------------------------------------------
// CSR build kernels
// ---------------------------------------------------------------------------
__global__ void k_hist(const int* __restrict__ dst, int* __restrict__ deg, int ne) {
    int e = blockIdx.x * 256 + threadIdx.x;
    if (e < ne) atomicAdd(&deg[dst[e]], 1);
}

// single block, 1024 threads: exclusive scan deg[0..N) -> rowptr[0..N]
__global__ __launch_bounds__(1024) void k_scan(const int* __restrict__ deg,
                                               int* __restrict__ rowptr) {
    __shared__ int sums[1024];
    const int C = 49;  // 1024*49 = 50176 >= 50001
    int t = threadIdx.x;
    int base = t * C;
    int s = 0;
    for (int i = 0; i < C; ++i) {
        int idx = base + i;
        if (idx < N_NODES) s += deg[idx];
    }
    sums[t] = s;
    __syncthreads();
    // Hillis-Steele inclusive scan
    for (int off = 1; off < 1024; off <<= 1) {
        int v = (t >= off) ? sums[t - off] : 0;
        __syncthreads();
        sums[t] += v;
        __syncthreads();
    }
    int run = (t == 0) ? 0 : sums[t - 1];
    for (int i = 0; i < C; ++i) {
        int idx = base + i;
        if (idx <= N_NODES) rowptr[idx] = run;
        if (idx < N_NODES) run += deg[idx];
    }
}

__global__ void k_fill(const int* __restrict__ src, const int* __restrict__ dst,
                       int* __restrict__ cursor, int* __restrict__ col, int ne) {
    int e = blockIdx.x * 256 + threadIdx.x;
    if (e < ne) {
        int p = atomicAdd(&cursor[dst[e]], 1);
        col[p] = src[e];
    }
}

// ---------------------------------------------------------------------------
// GEMM: G = X @ W, X: n x 128, W: 128 x 128 (row-major, W[k][c])
// block = 256 threads, 32 rows per block, 4x4 register tile, k-unroll 4
// ---------------------------------------------------------------------------
#define FMA4(a_, s_, v_) \
    do { (a_).x += (s_) * (v_).x; (a_).y += (s_) * (v_).y; \
         (a_).z += (s_) * (v_).z; (a_).w += (s_) * (v_).w; } while (0)

__global__ __launch_bounds__(256) void k_gemm128(const float* __restrict__ X,
                                                 const float* __restrict__ W,
                                                 float* __restrict__ G, int nrows) {
    __shared__ float Ws[128 * 128];
    __shared__ float Xs[32 * 128];
    int t = threadIdx.x;
    int rowbase = blockIdx.x * 32;

    const float4* W4 = (const float4*)W;
    float4* Ws4 = (float4*)Ws;
#pragma unroll
    for (int i = 0; i < 16; ++i) Ws4[t + i * 256] = W4[t + i * 256];

    const float4* X4 = (const float4*)X;
    float4* Xs4 = (float4*)Xs;
#pragma unroll
    for (int i = 0; i < 4; ++i) {
        int idx = t + i * 256;            // float4 index in 32x32 tile
        int r = rowbase + (idx >> 5);
        Xs4[idx] = (r < nrows) ? X4[r * 32 + (idx & 31)] : make_float4(0.f, 0.f, 0.f, 0.f);
    }
    __syncthreads();

    int cg = t & 31;   // cols = cg*4 .. cg*4+3
    int rg = t >> 5;   // rows = rg*4 .. rg*4+3
    float4 acc[4];
#pragma unroll
    for (int r = 0; r < 4; ++r) acc[r] = make_float4(0.f, 0.f, 0.f, 0.f);

    for (int kk = 0; kk < 32; ++kk) {
        float4 x0 = Xs4[(rg * 4 + 0) * 32 + kk];
        float4 x1 = Xs4[(rg * 4 + 1) * 32 + kk];
        float4 x2 = Xs4[(rg * 4 + 2) * 32 + kk];
        float4 x3 = Xs4[(rg * 4 + 3) * 32 + kk];
        float4 w0 = Ws4[(kk * 4 + 0) * 32 + cg];
        float4 w1 = Ws4[(kk * 4 + 1) * 32 + cg];
        float4 w2 = Ws4[(kk * 4 + 2) * 32 + cg];
        float4 w3 = Ws4[(kk * 4 + 3) * 32 + cg];
        FMA4(acc[0], x0.x, w0); FMA4(acc[0], x0.y, w1); FMA4(acc[0], x0.z, w2); FMA4(acc[0], x0.w, w3);
        FMA4(acc[1], x1.x, w0); FMA4(acc[1], x1.y, w1); FMA4(acc[1], x1.z, w2); FMA4(acc[1], x1.w, w3);
        FMA4(acc[2], x2.x, w0); FMA4(acc[2], x2.y, w1); FMA4(acc[2], x2.z, w2); FMA4(acc[2], x2.w, w3);
        FMA4(acc[3], x3.x, w0); FMA4(acc[3], x3.y, w1); FMA4(acc[3], x3.z, w2); FMA4(acc[3], x3.w, w3);
    }

#pragma unroll
    for (int r = 0; r < 4; ++r) {
        int row = rowbase + rg * 4 + r;
        if (row < nrows) ((float4*)G)[row * 32 + cg] = acc[r];
    }
}

// ---------------------------------------------------------------------------
// Gather+bias+ReLU: out[v] = act(g[v] + sum_{j} g[col[j]] + b), D=128
// one wave per node; lane owns float2 at d = lane*2
// ---------------------------------------------------------------------------
__global__ __launch_bounds__(256) void k_gather128(const float* __restrict__ g,
                                                   const int* __restrict__ rowptr,
                                                   const int* __restrict__ col,
                                                   const float* __restrict__ bias,
                                                   float* __restrict__ out,
                                                   int do_relu) {
    int node = blockIdx.x * 4 + (threadIdx.x >> 6);
    if (node >= N_NODES) return;
    int lane = threadIdx.x & 63;
    const float2* g2 = (const float2*)g;

    float2 bb = ((const float2*)bias)[lane];
    float2 self = g2[node * 64 + lane];
    float2 a0 = make_float2(self.x + bb.x, self.y + bb.y);
    float2 a1 = make_float2(0.f, 0.f);
    float2 a2 = make_float2(0.f, 0.f);
    float2 a3 = make_float2(0.f, 0.f);

    int s = rowptr[node], e = rowptr[node + 1];
    int j = s;
    for (; j + 3 < e; j += 4) {
        int u0 = col[j], u1 = col[j + 1], u2 = col[j + 2], u3 = col[j + 3];
        float2 v0 = g2[u0 * 64 + lane];
        float2 v1 = g2[u1 * 64 + lane];
        float2 v2 = g2[u2 * 64 + lane];
        float2 v3 = g2[u3 * 64 + lane];
        a0.x += v0.x; a0.y += v0.y;
        a1.x += v1.x; a1.y += v1.y;
        a2.x += v2.x; a2.y += v2.y;
        a3.x += v3.x; a3.y += v3.y;
    }
    for (; j < e; ++j) {
        int u = col[j];
        float2 v = g2[u * 64 + lane];
        a0.x += v.x; a0.y += v.y;
    }
    float2 acc = make_float2(a0.x + a1.x + a2.x + a3.x, a0.y + a1.y + a2.y + a3.y);
    if (do_relu) { acc.x = fmaxf(acc.x, 0.f); acc.y = fmaxf(acc.y, 0.f); }
    ((float2*)out)[node * 64 + lane] = acc;
}

// ---------------------------------------------------------------------------
// Final GEMM: Y = X @ W3, W3: 128 x 4.  4 threads per row, shfl reduce.
// ---------------------------------------------------------------------------
__global__ __launch_bounds__(256) void k_gemm_final(const float* __restrict__ X,
                                                    const float* __restrict__ W3,
                                                    float* __restrict__ Y, int nrows) {
    __shared__ float Ws[128 * 4];
    int t = threadIdx.x;
    if (t < 128) ((float4*)Ws)[t] = ((const float4*)W3)[t];
    __syncthreads();

    int idx = blockIdx.x * 256 + t;
    int row = idx >> 2;
    int q = idx & 3;
    if (row >= nrows) return;

    const float4* X4 = (const float4*)X;
    float acc[4] = {0.f, 0.f, 0.f, 0.f};
#pragma unroll
    for (int i = 0; i < 8; ++i) {
        float4 x = X4[row * 32 + q * 8 + i];
        int k = q * 32 + i * 4;
#pragma unroll
        for (int c = 0; c < 4; ++c) {
            acc[c] += x.x * Ws[(k + 0) * 4 + c] + x.y * Ws[(k + 1) * 4 + c]
                    + x.z * Ws[(k + 2) * 4 + c] + x.w * Ws[(k + 3) * 4 + c];
        }
    }
#pragma unroll
    for (int off = 1; off < 4; off <<= 1) {
#pragma unroll
        for (int c = 0; c < 4; ++c) acc[c] += __shfl_xor(acc[c], off, 64);
    }
    if (q == 0) ((float4*)Y)[row] = make_float4(acc[0], acc[1], acc[2], acc[3]);
}

// ---------------------------------------------------------------------------
// Final gather: out[v] = y[v] + sum_j y[col[j]] + b3   (4 floats per node)
// ---------------------------------------------------------------------------
__global__ __launch_bounds__(256) void k_gather4(const float* __restrict__ y,
                                                 const int* __restrict__ rowptr,
                                                 const int* __restrict__ col,
                                                 const float* __restrict__ b3,
                                                 float* __restrict__ out) {
    int v = blockIdx.x * 256 + threadIdx.x;
    if (v >= N_NODES) return;
    const float4* y4 = (const float4*)y;
    float4 acc = y4[v];
    float4 bb = *(const float4*)b3;
    acc.x += bb.x; acc.y += bb.y; acc.z += bb.z; acc.w += bb.w;
    int s = rowptr[v], e = rowptr[v + 1];
    for (int j = s; j < e; ++j) {
        float4 t = y4[col[j]];
        acc.x += t.x; acc.y += t.y; acc.z += t.z; acc.w += t.w;
    }
    ((float4*)out)[v] = acc;
}

// ---------------------------------------------------------------------------
extern "C" void kernel_launch(void* const* d_in, const int* in_sizes, int n_in,
                              void* d_out, int out_size, void* d_ws, size_t ws_size,
                              hipStream_t stream) {
    const float* feat = (const float*)d_in[0];
    const int*   src  = (const int*)d_in[1];
    const int*   dst  = (const int*)d_in[2];
    const float* W0 = (const float*)d_in[3];
    const float* b0 = (const float*)d_in[4];
    const float* W1 = (const float*)d_in[5];
    const float* b1 = (const float*)d_in[6];
    const float* W2 = (const float*)d_in[7];
    const float* b2 = (const float*)d_in[8];
    const float* W3 = (const float*)d_in[9];
    const float* b3 = (const float*)d_in[10];

    const int n  = N_NODES;
    const int ne = in_sizes[1];

    // workspace layout (256B aligned)
    char* p = (char*)d_ws;
    auto alloc = [&](size_t bytes) {
        char* r = p;
        p += (bytes + 255) & ~(size_t)255;
        return r;
    };
    int*   rowptr = (int*)alloc((n + 1) * sizeof(int));
    int*   tmp    = (int*)alloc(n * sizeof(int));        // deg, then cursor
    int*   col    = (int*)alloc(ne * sizeof(int));
    float* g      = (float*)alloc((size_t)n * 128 * sizeof(float));
    float* hA     = (float*)alloc((size_t)n * 128 * sizeof(float));
    float* hB     = (float*)alloc((size_t)n * 128 * sizeof(float));
    float* y      = (float*)alloc((size_t)n * 4 * sizeof(float));
    float* outf   = (float*)d_out;

    int eb = (ne + 255) / 256;
    int gemmb = (n + 31) / 32;
    int gathb = (n + 3) / 4;
    int nb256 = (n + 255) / 256;

    // --- CSR build ---
    hipMemsetAsync(tmp, 0, n * sizeof(int), stream);
    k_hist<<<eb, 256, 0, stream>>>(dst, tmp, ne);
    k_scan<<<1, 1024, 0, stream>>>(tmp, rowptr);
    hipMemcpyAsync(tmp, rowptr, n * sizeof(int), hipMemcpyDeviceToDevice, stream);
    k_fill<<<eb, 256, 0, stream>>>(src, dst, tmp, col, ne);

    // --- layer 0 ---
    k_gemm128<<<gemmb, 256, 0, stream>>>(feat, W0, g, n);
    k_gather128<<<gathb, 256, 0, stream>>>(g, rowptr, col, b0, hA, 1);
    // --- layer 1 ---
    k_gemm128<<<gemmb, 256, 0, stream>>>(hA, W1, g, n);
    k_gather128<<<gathb, 256, 0, stream>>>(g, rowptr, col, b1, hB, 1);
    // --- layer 2 ---
    k_gemm128<<<gemmb, 256, 0, stream>>>(hB, W2, g, n);
    k_gather128<<<gathb, 256, 0, stream>>>(g, rowptr, col, b2, hA, 1);
    // --- layer 3 (output dim 4) ---
    k_gemm_final<<<(n * 4 + 255) / 256, 256, 0, stream>>>(hA, W3, y, n);
    k_gather4<<<nb256, 256, 0, stream>>>(y, rowptr, col, b3, outf);
}

// Round 3
// 685.690 us; speedup vs baseline: 1.1700x; 1.1700x over previous
//
#include <hip/hip_runtime.h>
#include <hip/hip_bf16.h>

#define N_NODES 50000

// ---------------------------------------------------------------------------
// helpers
// ---------------------------------------------------------------------------
__device__ __forceinline__ unsigned short f2bf(float f) {
    unsigned int u = __float_as_uint(f);
    unsigned int r = (u + 0x7fffu + ((u >> 16) & 1u)) >> 16;   // RNE
    return (unsigned short)r;
}

// ---------------------------------------------------------------------------
// CSR build kernels
// ---------------------------------------------------------------------------
__global__ void k_hist(const int* __restrict__ dst, int* __restrict__ deg, int ne) {
    int e = blockIdx.x * 256 + threadIdx.x;
    if (e < ne) atomicAdd(&deg[dst[e]], 1);
}

// single block, 1024 threads: exclusive scan deg[0..N) -> rowptr[0..N] and cursor copy
__global__ __launch_bounds__(1024) void k_scan(const int* __restrict__ deg,
                                               int* __restrict__ rowptr,
                                               int* __restrict__ cursor) {
    __shared__ int sums[1024];
    const int C = 49;  // 1024*49 = 50176 >= 50001
    int t = threadIdx.x;
    int base = t * C;
    int s = 0;
    for (int i = 0; i < C; ++i) {
        int idx = base + i;
        if (idx < N_NODES) s += deg[idx];
    }
    sums[t] = s;
    __syncthreads();
    for (int off = 1; off < 1024; off <<= 1) {
        int v = (t >= off) ? sums[t - off] : 0;
        __syncthreads();
        sums[t] += v;
        __syncthreads();
    }
    int run = (t == 0) ? 0 : sums[t - 1];
    for (int i = 0; i < C; ++i) {
        int idx = base + i;
        if (idx <= N_NODES) rowptr[idx] = run;
        if (idx < N_NODES) {
            cursor[idx] = run;
            run += deg[idx];
        }
    }
}

__global__ void k_fill(const int* __restrict__ src, const int* __restrict__ dst,
                       int* __restrict__ cursor, int* __restrict__ col, int ne) {
    int e = blockIdx.x * 256 + threadIdx.x;
    if (e < ne) {
        int p = atomicAdd(&cursor[dst[e]], 1);
        col[p] = src[e];
    }
}

// ---------------------------------------------------------------------------
// GEMM: G(bf16) = X(f32) @ W, X: n x 128, W: 128 x 128 (row-major, W[k][c])
// block = 256 threads, 32 rows per block, 4x4 register tile
// ---------------------------------------------------------------------------
#define FMA4(a_, s_, v_) \
    do { (a_).x += (s_) * (v_).x; (a_).y += (s_) * (v_).y; \
         (a_).z += (s_) * (v_).z; (a_).w += (s_) * (v_).w; } while (0)

__global__ __launch_bounds__(256) void k_gemm128(const float* __restrict__ X,
                                                 const float* __restrict__ W,
                                                 unsigned short* __restrict__ G,
                                                 int nrows) {
    __shared__ float Ws[128 * 128];
    __shared__ float Xs[32 * 128];
    int t = threadIdx.x;
    int rowbase = blockIdx.x * 32;

    const float4* W4 = (const float4*)W;
    float4* Ws4 = (float4*)Ws;
#pragma unroll
    for (int i = 0; i < 16; ++i) Ws4[t + i * 256] = W4[t + i * 256];

    const float4* X4 = (const float4*)X;
    float4* Xs4 = (float4*)Xs;
#pragma unroll
    for (int i = 0; i < 4; ++i) {
        int idx = t + i * 256;            // float4 index in 32x32 tile
        int r = rowbase + (idx >> 5);
        Xs4[idx] = (r < nrows) ? X4[r * 32 + (idx & 31)] : make_float4(0.f, 0.f, 0.f, 0.f);
    }
    __syncthreads();

    int cg = t & 31;   // cols = cg*4 .. cg*4+3
    int rg = t >> 5;   // rows = rg*4 .. rg*4+3
    float4 acc[4];
#pragma unroll
    for (int r = 0; r < 4; ++r) acc[r] = make_float4(0.f, 0.f, 0.f, 0.f);

    for (int kk = 0; kk < 32; ++kk) {
        float4 x0 = Xs4[(rg * 4 + 0) * 32 + kk];
        float4 x1 = Xs4[(rg * 4 + 1) * 32 + kk];
        float4 x2 = Xs4[(rg * 4 + 2) * 32 + kk];
        float4 x3 = Xs4[(rg * 4 + 3) * 32 + kk];
        float4 w0 = Ws4[(kk * 4 + 0) * 32 + cg];
        float4 w1 = Ws4[(kk * 4 + 1) * 32 + cg];
        float4 w2 = Ws4[(kk * 4 + 2) * 32 + cg];
        float4 w3 = Ws4[(kk * 4 + 3) * 32 + cg];
        FMA4(acc[0], x0.x, w0); FMA4(acc[0], x0.y, w1); FMA4(acc[0], x0.z, w2); FMA4(acc[0], x0.w, w3);
        FMA4(acc[1], x1.x, w0); FMA4(acc[1], x1.y, w1); FMA4(acc[1], x1.z, w2); FMA4(acc[1], x1.w, w3);
        FMA4(acc[2], x2.x, w0); FMA4(acc[2], x2.y, w1); FMA4(acc[2], x2.z, w2); FMA4(acc[2], x2.w, w3);
        FMA4(acc[3], x3.x, w0); FMA4(acc[3], x3.y, w1); FMA4(acc[3], x3.z, w2); FMA4(acc[3], x3.w, w3);
    }

#pragma unroll
    for (int r = 0; r < 4; ++r) {
        int row = rowbase + rg * 4 + r;
        if (row < nrows) {
            ushort4 o;
            o.x = f2bf(acc[r].x); o.y = f2bf(acc[r].y);
            o.z = f2bf(acc[r].z); o.w = f2bf(acc[r].w);
            *(ushort4*)(G + (size_t)row * 128 + cg * 4) = o;
        }
    }
}

// ---------------------------------------------------------------------------
// Gather+bias+ReLU from bf16 g: out[v] = act(g[v] + sum_j g[col[j]] + b)
// one wave per node; lane owns 2 bf16 at d = lane*2 (one uint load)
// ---------------------------------------------------------------------------
__global__ __launch_bounds__(256) void k_gather128(const unsigned short* __restrict__ g,
                                                   const int* __restrict__ rowptr,
                                                   const int* __restrict__ col,
                                                   const float* __restrict__ bias,
                                                   float* __restrict__ out,
                                                   int do_relu) {
    int node = blockIdx.x * 4 + (threadIdx.x >> 6);
    if (node >= N_NODES) return;
    int lane = threadIdx.x & 63;
    const unsigned int* g2 = (const unsigned int*)g;

    float2 bb = ((const float2*)bias)[lane];
    unsigned int sv = g2[(size_t)node * 64 + lane];
    float2 a0 = make_float2(bb.x + __uint_as_float(sv << 16),
                            bb.y + __uint_as_float(sv & 0xffff0000u));
    float2 a1 = make_float2(0.f, 0.f);
    float2 a2 = make_float2(0.f, 0.f);
    float2 a3 = make_float2(0.f, 0.f);

    int s = rowptr[node], e = rowptr[node + 1];
    int j = s;
    for (; j + 3 < e; j += 4) {
        int u0 = col[j], u1 = col[j + 1], u2 = col[j + 2], u3 = col[j + 3];
        unsigned int v0 = g2[(size_t)u0 * 64 + lane];
        unsigned int v1 = g2[(size_t)u1 * 64 + lane];
        unsigned int v2 = g2[(size_t)u2 * 64 + lane];
        unsigned int v3 = g2[(size_t)u3 * 64 + lane];
        a0.x += __uint_as_float(v0 << 16); a0.y += __uint_as_float(v0 & 0xffff0000u);
        a1.x += __uint_as_float(v1 << 16); a1.y += __uint_as_float(v1 & 0xffff0000u);
        a2.x += __uint_as_float(v2 << 16); a2.y += __uint_as_float(v2 & 0xffff0000u);
        a3.x += __uint_as_float(v3 << 16); a3.y += __uint_as_float(v3 & 0xffff0000u);
    }
    for (; j < e; ++j) {
        int u = col[j];
        unsigned int v = g2[(size_t)u * 64 + lane];
        a0.x += __uint_as_float(v << 16); a0.y += __uint_as_float(v & 0xffff0000u);
    }
    float2 acc = make_float2(a0.x + a1.x + a2.x + a3.x, a0.y + a1.y + a2.y + a3.y);
    if (do_relu) { acc.x = fmaxf(acc.x, 0.f); acc.y = fmaxf(acc.y, 0.f); }
    ((float2*)out)[(size_t)node * 64 + lane] = acc;
}

// ---------------------------------------------------------------------------
// Final GEMM: Y = X @ W3, W3: 128 x 4.  4 threads per row, shfl reduce.
// ---------------------------------------------------------------------------
__global__ __launch_bounds__(256) void k_gemm_final(const float* __restrict__ X,
                                                    const float* __restrict__ W3,
                                                    float* __restrict__ Y, int nrows) {
    __shared__ float Ws[128 * 4];
    int t = threadIdx.x;
    if (t < 128) ((float4*)Ws)[t] = ((const float4*)W3)[t];
    __syncthreads();

    int idx = blockIdx.x * 256 + t;
    int row = idx >> 2;
    int q = idx & 3;
    if (row >= nrows) return;

    const float4* X4 = (const float4*)X;
    float acc[4] = {0.f, 0.f, 0.f, 0.f};
#pragma unroll
    for (int i = 0; i < 8; ++i) {
        float4 x = X4[row * 32 + q * 8 + i];
        int k = q * 32 + i * 4;
#pragma unroll
        for (int c = 0; c < 4; ++c) {
            acc[c] += x.x * Ws[(k + 0) * 4 + c] + x.y * Ws[(k + 1) * 4 + c]
                    + x.z * Ws[(k + 2) * 4 + c] + x.w * Ws[(k + 3) * 4 + c];
        }
    }
#pragma unroll
    for (int off = 1; off < 4; off <<= 1) {
#pragma unroll
        for (int c = 0; c < 4; ++c) acc[c] += __shfl_xor(acc[c], off, 64);
    }
    if (q == 0) ((float4*)Y)[row] = make_float4(acc[0], acc[1], acc[2], acc[3]);
}

// ---------------------------------------------------------------------------
// Final gather: out[v] = y[v] + sum_j y[col[j]] + b3   (4 floats per node)
// ---------------------------------------------------------------------------
__global__ __launch_bounds__(256) void k_gather4(const float* __restrict__ y,
                                                 const int* __restrict__ rowptr,
                                                 const int* __restrict__ col,
                                                 const float* __restrict__ b3,
                                                 float* __restrict__ out) {
    int v = blockIdx.x * 256 + threadIdx.x;
    if (v >= N_NODES) return;
    const float4* y4 = (const float4*)y;
    float4 acc = y4[v];
    float4 bb = *(const float4*)b3;
    acc.x += bb.x; acc.y += bb.y; acc.z += bb.z; acc.w += bb.w;
    int s = rowptr[v], e = rowptr[v + 1];
    for (int j = s; j < e; ++j) {
        float4 t = y4[col[j]];
        acc.x += t.x; acc.y += t.y; acc.z += t.z; acc.w += t.w;
    }
    ((float4*)out)[v] = acc;
}

// ---------------------------------------------------------------------------
extern "C" void kernel_launch(void* const* d_in, const int* in_sizes, int n_in,
                              void* d_out, int out_size, void* d_ws, size_t ws_size,
                              hipStream_t stream) {
    const float* feat = (const float*)d_in[0];
    const int*   src  = (const int*)d_in[1];
    const int*   dst  = (const int*)d_in[2];
    const float* W0 = (const float*)d_in[3];
    const float* b0 = (const float*)d_in[4];
    const float* W1 = (const float*)d_in[5];
    const float* b1 = (const float*)d_in[6];
    const float* W2 = (const float*)d_in[7];
    const float* b2 = (const float*)d_in[8];
    const float* W3 = (const float*)d_in[9];
    const float* b3 = (const float*)d_in[10];

    const int n  = N_NODES;
    const int ne = in_sizes[1];

    // workspace layout (256B aligned)
    char* p = (char*)d_ws;
    auto alloc = [&](size_t bytes) {
        char* r = p;
        p += (bytes + 255) & ~(size_t)255;
        return r;
    };
    int*   rowptr = (int*)alloc((n + 1) * sizeof(int));
    int*   deg    = (int*)alloc(n * sizeof(int));
    int*   cursor = (int*)alloc(n * sizeof(int));
    int*   col    = (int*)alloc(ne * sizeof(int));
    unsigned short* g = (unsigned short*)alloc((size_t)n * 128 * sizeof(unsigned short));
    float* hA     = (float*)alloc((size_t)n * 128 * sizeof(float));
    float* hB     = (float*)alloc((size_t)n * 128 * sizeof(float));
    float* y      = (float*)alloc((size_t)n * 4 * sizeof(float));
    float* outf   = (float*)d_out;

    int eb = (ne + 255) / 256;
    int gemmb = (n + 31) / 32;
    int gathb = (n + 3) / 4;
    int nb256 = (n + 255) / 256;

    // --- CSR build ---
    hipMemsetAsync(deg, 0, n * sizeof(int), stream);
    k_hist<<<eb, 256, 0, stream>>>(dst, deg, ne);
    k_scan<<<1, 1024, 0, stream>>>(deg, rowptr, cursor);
    k_fill<<<eb, 256, 0, stream>>>(src, dst, cursor, col, ne);

    // --- layer 0 ---
    k_gemm128<<<gemmb, 256, 0, stream>>>(feat, W0, g, n);
    k_gather128<<<gathb, 256, 0, stream>>>(g, rowptr, col, b0, hA, 1);
    // --- layer 1 ---
    k_gemm128<<<gemmb, 256, 0, stream>>>(hA, W1, g, n);
    k_gather128<<<gathb, 256, 0, stream>>>(g, rowptr, col, b1, hB, 1);
    // --- layer 2 ---
    k_gemm128<<<gemmb, 256, 0, stream>>>(hB, W2, g, n);
    k_gather128<<<gathb, 256, 0, stream>>>(g, rowptr, col, b2, hA, 1);
    // --- layer 3 (output dim 4) ---
    k_gemm_final<<<(n * 4 + 255) / 256, 256, 0, stream>>>(hA, W3, y, n);
    k_gather4<<<nb256, 256, 0, stream>>>(y, rowptr, col, b3, outf);
}

// Round 7
// 555.682 us; speedup vs baseline: 1.4437x; 1.2340x over previous
//
#include <hip/hip_runtime.h>
#include <hip/hip_bf16.h>

#define N_NODES 50000
#define NSLICE 8
#define SLICE_SZ 6250   // N_NODES / NSLICE exactly

// ---------------------------------------------------------------------------
// helpers
// ---------------------------------------------------------------------------
__device__ __forceinline__ unsigned short f2bf(float f) {
    unsigned int u = __float_as_uint(f);
    unsigned int r = (u + 0x7fffu + ((u >> 16) & 1u)) >> 16;   // RNE
    return (unsigned short)r;
}

// ---------------------------------------------------------------------------
// CSR build kernels
// ---------------------------------------------------------------------------
__global__ void k_hist(const int* __restrict__ dst, int* __restrict__ deg, int ne) {
    int e = blockIdx.x * 256 + threadIdx.x;
    if (e < ne) atomicAdd(&deg[dst[e]], 1);
}

// 49 blocks x 1024: per-block sum of deg
__global__ __launch_bounds__(1024) void k_blocksum(const int* __restrict__ deg,
                                                   int* __restrict__ bsum) {
    int i = blockIdx.x * 1024 + threadIdx.x;
    int v = (i < N_NODES) ? deg[i] : 0;
#pragma unroll
    for (int off = 32; off >= 1; off >>= 1) v += __shfl_down(v, off, 64);
    __shared__ int ws[16];
    if ((threadIdx.x & 63) == 0) ws[threadIdx.x >> 6] = v;
    __syncthreads();
    if (threadIdx.x < 16) {
        int s = ws[threadIdx.x];
#pragma unroll
        for (int off = 8; off >= 1; off >>= 1) s += __shfl_down(s, off, 16);
        if (threadIdx.x == 0) bsum[blockIdx.x] = s;
    }
}

// 49 blocks x 1024: local scan + block prefix -> rowptr, cursor
__global__ __launch_bounds__(1024) void k_scan2(const int* __restrict__ deg,
                                                const int* __restrict__ bsum,
                                                int* __restrict__ rowptr,
                                                int* __restrict__ cursor) {
    __shared__ int lds[1024];
    int b = blockIdx.x, t = threadIdx.x;
    int prefix = 0;
    for (int k = 0; k < b; ++k) prefix += bsum[k];
    int i = b * 1024 + t;
    int v = (i < N_NODES) ? deg[i] : 0;
    lds[t] = v;
    __syncthreads();
    for (int off = 1; off < 1024; off <<= 1) {
        int x = (t >= off) ? lds[t - off] : 0;
        __syncthreads();
        lds[t] += x;
        __syncthreads();
    }
    int excl = prefix + lds[t] - v;
    if (i <= N_NODES) {
        rowptr[i] = excl;
        if (i < N_NODES) cursor[i] = excl;
    }
}

// XCD-sliced fill: blocks with blockIdx%8==s handle dst in [s*6250,(s+1)*6250)
__global__ __launch_bounds__(256) void k_fill(const int* __restrict__ src,
                                              const int* __restrict__ dst,
                                              int* __restrict__ cursor,
                                              int* __restrict__ col,
                                              int ne, int chunk) {
    int slice = blockIdx.x & (NSLICE - 1);
    int grp   = blockIdx.x >> 3;
    int lo = slice * SLICE_SZ;
    int hi = lo + SLICE_SZ;
    int start = grp * chunk;
    int end = start + chunk;
    if (end > ne) end = ne;
    for (int e = start + threadIdx.x; e < end; e += 256) {
        int d = dst[e];
        if (d >= lo && d < hi) {
            int p = atomicAdd(&cursor[d], 1);
            col[p] = src[e];
        }
    }
}

// ---------------------------------------------------------------------------
// GEMM: G(bf16) = X(f32) @ W, X: n x 128, W: 128 x 128 (row-major, W[k][c])
// block = 256 threads, 32 rows per block, 4x4 register tile
// ---------------------------------------------------------------------------
#define FMA4(a_, s_, v_) \
    do { (a_).x += (s_) * (v_).x; (a_).y += (s_) * (v_).y; \
         (a_).z += (s_) * (v_).z; (a_).w += (s_) * (v_).w; } while (0)

__global__ __launch_bounds__(256) void k_gemm128(const float* __restrict__ X,
                                                 const float* __restrict__ W,
                                                 unsigned short* __restrict__ G,
                                                 int nrows) {
    __shared__ float Ws[128 * 128];
    __shared__ float Xs[32 * 128];
    int t = threadIdx.x;
    int rowbase = blockIdx.x * 32;

    const float4* W4 = (const float4*)W;
    float4* Ws4 = (float4*)Ws;
#pragma unroll
    for (int i = 0; i < 16; ++i) Ws4[t + i * 256] = W4[t + i * 256];

    const float4* X4 = (const float4*)X;
    float4* Xs4 = (float4*)Xs;
#pragma unroll
    for (int i = 0; i < 4; ++i) {
        int idx = t + i * 256;            // float4 index in 32x32 tile
        int r = rowbase + (idx >> 5);
        Xs4[idx] = (r < nrows) ? X4[r * 32 + (idx & 31)] : make_float4(0.f, 0.f, 0.f, 0.f);
    }
    __syncthreads();

    int cg = t & 31;   // cols = cg*4 .. cg*4+3
    int rg = t >> 5;   // rows = rg*4 .. rg*4+3
    float4 acc[4];
#pragma unroll
    for (int r = 0; r < 4; ++r) acc[r] = make_float4(0.f, 0.f, 0.f, 0.f);

    for (int kk = 0; kk < 32; ++kk) {
        float4 x0 = Xs4[(rg * 4 + 0) * 32 + kk];
        float4 x1 = Xs4[(rg * 4 + 1) * 32 + kk];
        float4 x2 = Xs4[(rg * 4 + 2) * 32 + kk];
        float4 x3 = Xs4[(rg * 4 + 3) * 32 + kk];
        float4 w0 = Ws4[(kk * 4 + 0) * 32 + cg];
        float4 w1 = Ws4[(kk * 4 + 1) * 32 + cg];
        float4 w2 = Ws4[(kk * 4 + 2) * 32 + cg];
        float4 w3 = Ws4[(kk * 4 + 3) * 32 + cg];
        FMA4(acc[0], x0.x, w0); FMA4(acc[0], x0.y, w1); FMA4(acc[0], x0.z, w2); FMA4(acc[0], x0.w, w3);
        FMA4(acc[1], x1.x, w0); FMA4(acc[1], x1.y, w1); FMA4(acc[1], x1.z, w2); FMA4(acc[1], x1.w, w3);
        FMA4(acc[2], x2.x, w0); FMA4(acc[2], x2.y, w1); FMA4(acc[2], x2.z, w2); FMA4(acc[2], x2.w, w3);
        FMA4(acc[3], x3.x, w0); FMA4(acc[3], x3.y, w1); FMA4(acc[3], x3.z, w2); FMA4(acc[3], x3.w, w3);
    }

#pragma unroll
    for (int r = 0; r < 4; ++r) {
        int row = rowbase + rg * 4 + r;
        if (row < nrows) {
            ushort4 o;
            o.x = f2bf(acc[r].x); o.y = f2bf(acc[r].y);
            o.z = f2bf(acc[r].z); o.w = f2bf(acc[r].w);
            *(ushort4*)(G + (size_t)row * 128 + cg * 4) = o;
        }
    }
}

// ---------------------------------------------------------------------------
// Gather+bias+ReLU from bf16 g: out[v] = act(g[v] + sum_j g[col[j]] + b)
// one wave per node; lane owns 2 bf16 at d = lane*2 (one uint load)
// ---------------------------------------------------------------------------
__global__ __launch_bounds__(256) void k_gather128(const unsigned short* __restrict__ g,
                                                   const int* __restrict__ rowptr,
                                                   const int* __restrict__ col,
                                                   const float* __restrict__ bias,
                                                   float* __restrict__ out,
                                                   int do_relu) {
    int node = blockIdx.x * 4 + (threadIdx.x >> 6);
    if (node >= N_NODES) return;
    int lane = threadIdx.x & 63;
    const unsigned int* g2 = (const unsigned int*)g;

    float2 bb = ((const float2*)bias)[lane];
    unsigned int sv = g2[(size_t)node * 64 + lane];
    float2 a0 = make_float2(bb.x + __uint_as_float(sv << 16),
                            bb.y + __uint_as_float(sv & 0xffff0000u));
    float2 a1 = make_float2(0.f, 0.f);
    float2 a2 = make_float2(0.f, 0.f);
    float2 a3 = make_float2(0.f, 0.f);

    int s = rowptr[node], e = rowptr[node + 1];
    int j = s;
    for (; j + 3 < e; j += 4) {
        int u0 = col[j], u1 = col[j + 1], u2 = col[j + 2], u3 = col[j + 3];
        unsigned int v0 = g2[(size_t)u0 * 64 + lane];
        unsigned int v1 = g2[(size_t)u1 * 64 + lane];
        unsigned int v2 = g2[(size_t)u2 * 64 + lane];
        unsigned int v3 = g2[(size_t)u3 * 64 + lane];
        a0.x += __uint_as_float(v0 << 16); a0.y += __uint_as_float(v0 & 0xffff0000u);
        a1.x += __uint_as_float(v1 << 16); a1.y += __uint_as_float(v1 & 0xffff0000u);
        a2.x += __uint_as_float(v2 << 16); a2.y += __uint_as_float(v2 & 0xffff0000u);
        a3.x += __uint_as_float(v3 << 16); a3.y += __uint_as_float(v3 & 0xffff0000u);
    }
    for (; j < e; ++j) {
        int u = col[j];
        unsigned int v = g2[(size_t)u * 64 + lane];
        a0.x += __uint_as_float(v << 16); a0.y += __uint_as_float(v & 0xffff0000u);
    }
    float2 acc = make_float2(a0.x + a1.x + a2.x + a3.x, a0.y + a1.y + a2.y + a3.y);
    if (do_relu) { acc.x = fmaxf(acc.x, 0.f); acc.y = fmaxf(acc.y, 0.f); }
    ((float2*)out)[(size_t)node * 64 + lane] = acc;
}

// ---------------------------------------------------------------------------
// Final GEMM: Y = X @ W3, W3: 128 x 4.  4 threads per row, shfl reduce.
// ---------------------------------------------------------------------------
__global__ __launch_bounds__(256) void k_gemm_final(const float* __restrict__ X,
                                                    const float* __restrict__ W3,
                                                    float* __restrict__ Y, int nrows) {
    __shared__ float Ws[128 * 4];
    int t = threadIdx.x;
    if (t < 128) ((float4*)Ws)[t] = ((const float4*)W3)[t];
    __syncthreads();

    int idx = blockIdx.x * 256 + t;
    int row = idx >> 2;
    int q = idx & 3;
    if (row >= nrows) return;

    const float4* X4 = (const float4*)X;
    float acc[4] = {0.f, 0.f, 0.f, 0.f};
#pragma unroll
    for (int i = 0; i < 8; ++i) {
        float4 x = X4[row * 32 + q * 8 + i];
        int k = q * 32 + i * 4;
#pragma unroll
        for (int c = 0; c < 4; ++c) {
            acc[c] += x.x * Ws[(k + 0) * 4 + c] + x.y * Ws[(k + 1) * 4 + c]
                    + x.z * Ws[(k + 2) * 4 + c] + x.w * Ws[(k + 3) * 4 + c];
        }
    }
#pragma unroll
    for (int off = 1; off < 4; off <<= 1) {
#pragma unroll
        for (int c = 0; c < 4; ++c) acc[c] += __shfl_xor(acc[c], off, 64);
    }
    if (q == 0) ((float4*)Y)[row] = make_float4(acc[0], acc[1], acc[2], acc[3]);
}

// ---------------------------------------------------------------------------
// Final gather: out[v] = y[v] + sum_j y[col[j]] + b3   (4 floats per node)
// ---------------------------------------------------------------------------
__global__ __launch_bounds__(256) void k_gather4(const float* __restrict__ y,
                                                 const int* __restrict__ rowptr,
                                                 const int* __restrict__ col,
                                                 const float* __restrict__ b3,
                                                 float* __restrict__ out) {
    int v = blockIdx.x * 256 + threadIdx.x;
    if (v >= N_NODES) return;
    const float4* y4 = (const float4*)y;
    float4 acc = y4[v];
    float4 bb = *(const float4*)b3;
    acc.x += bb.x; acc.y += bb.y; acc.z += bb.z; acc.w += bb.w;
    int s = rowptr[v], e = rowptr[v + 1];
    for (int j = s; j < e; ++j) {
        float4 t = y4[col[j]];
        acc.x += t.x; acc.y += t.y; acc.z += t.z; acc.w += t.w;
    }
    ((float4*)out)[v] = acc;
}

// ---------------------------------------------------------------------------
extern "C" void kernel_launch(void* const* d_in, const int* in_sizes, int n_in,
                              void* d_out, int out_size, void* d_ws, size_t ws_size,
                              hipStream_t stream) {
    const float* feat = (const float*)d_in[0];
    const int*   src  = (const int*)d_in[1];
    const int*   dst  = (const int*)d_in[2];
    const float* W0 = (const float*)d_in[3];
    const float* b0 = (const float*)d_in[4];
    const float* W1 = (const float*)d_in[5];
    const float* b1 = (const float*)d_in[6];
    const float* W2 = (const float*)d_in[7];
    const float* b2 = (const float*)d_in[8];
    const float* W3 = (const float*)d_in[9];
    const float* b3 = (const float*)d_in[10];

    const int n  = N_NODES;
    const int ne = in_sizes[1];

    // workspace layout (256B aligned)
    char* p = (char*)d_ws;
    auto alloc = [&](size_t bytes) {
        char* r = p;
        p += (bytes + 255) & ~(size_t)255;
        return r;
    };
    int*   rowptr = (int*)alloc((n + 1) * sizeof(int));
    int*   deg    = (int*)alloc(n * sizeof(int));
    int*   cursor = (int*)alloc(n * sizeof(int));
    int*   bsum   = (int*)alloc(64 * sizeof(int));
    int*   col    = (int*)alloc(ne * sizeof(int));
    unsigned short* g = (unsigned short*)alloc((size_t)n * 128 * sizeof(unsigned short));
    float* hA     = (float*)alloc((size_t)n * 128 * sizeof(float));
    float* hB     = (float*)alloc((size_t)n * 128 * sizeof(float));
    float* y      = (float*)alloc((size_t)n * 4 * sizeof(float));
    float* outf   = (float*)d_out;

    int eb = (ne + 255) / 256;
    int gemmb = (n + 31) / 32;
    int gathb = (n + 3) / 4;
    int nb256 = (n + 255) / 256;
    int scanb = (n + 1023) / 1024;           // 49

    // sliced fill config: 64 blocks per slice
    const int BPS = 64;
    int chunk = (ne + BPS - 1) / BPS;

    // --- CSR build ---
    hipMemsetAsync(deg, 0, n * sizeof(int), stream);
    k_hist<<<eb, 256, 0, stream>>>(dst, deg, ne);
    k_blocksum<<<scanb, 1024, 0, stream>>>(deg, bsum);
    k_scan2<<<scanb, 1024, 0, stream>>>(deg, bsum, rowptr, cursor);
    k_fill<<<NSLICE * BPS, 256, 0, stream>>>(src, dst, cursor, col, ne, chunk);

    // --- layer 0 ---
    k_gemm128<<<gemmb, 256, 0, stream>>>(feat, W0, g, n);
    k_gather128<<<gathb, 256, 0, stream>>>(g, rowptr, col, b0, hA, 1);
    // --- layer 1 ---
    k_gemm128<<<gemmb, 256, 0, stream>>>(hA, W1, g, n);
    k_gather128<<<gathb, 256, 0, stream>>>(g, rowptr, col, b1, hB, 1);
    // --- layer 2 ---
    k_gemm128<<<gemmb, 256, 0, stream>>>(hB, W2, g, n);
    k_gather128<<<gathb, 256, 0, stream>>>(g, rowptr, col, b2, hA, 1);
    // --- layer 3 (output dim 4) ---
    k_gemm_final<<<(n * 4 + 255) / 256, 256, 0, stream>>>(hA, W3, y, n);
    k_gather4<<<nb256, 256, 0, stream>>>(y, rowptr, col, b3, outf);
}

// Round 9
// 533.117 us; speedup vs baseline: 1.5048x; 1.0423x over previous
//
#include <hip/hip_runtime.h>
#include <hip/hip_bf16.h>

#define N_NODES 50000
#define NSLICE 8
#define SLICE_SZ 6250   // N_NODES / NSLICE exactly

// ---------------------------------------------------------------------------
// helpers
// ---------------------------------------------------------------------------
__device__ __forceinline__ unsigned short f2bf(float f) {
    unsigned int u = __float_as_uint(f);
    unsigned int r = (u + 0x7fffu + ((u >> 16) & 1u)) >> 16;   // RNE
    return (unsigned short)r;
}

// ---------------------------------------------------------------------------
// CSR build kernels
// ---------------------------------------------------------------------------
__global__ void k_hist(const int* __restrict__ dst, int* __restrict__ deg, int ne) {
    int e = blockIdx.x * 256 + threadIdx.x;
    if (e < ne) {
        int d = __builtin_nontemporal_load(dst + e);
        atomicAdd(&deg[d], 1);
    }
}

// 49 blocks x 1024: per-block sum of deg
__global__ __launch_bounds__(1024) void k_blocksum(const int* __restrict__ deg,
                                                   int* __restrict__ bsum) {
    int i = blockIdx.x * 1024 + threadIdx.x;
    int v = (i < N_NODES) ? deg[i] : 0;
#pragma unroll
    for (int off = 32; off >= 1; off >>= 1) v += __shfl_down(v, off, 64);
    __shared__ int ws[16];
    if ((threadIdx.x & 63) == 0) ws[threadIdx.x >> 6] = v;
    __syncthreads();
    if (threadIdx.x < 16) {
        int s = ws[threadIdx.x];
#pragma unroll
        for (int off = 8; off >= 1; off >>= 1) s += __shfl_down(s, off, 16);
        if (threadIdx.x == 0) bsum[blockIdx.x] = s;
    }
}

// 49 blocks x 1024: local scan + block prefix -> rowptr, cursor
__global__ __launch_bounds__(1024) void k_scan2(const int* __restrict__ deg,
                                                const int* __restrict__ bsum,
                                                int* __restrict__ rowptr,
                                                int* __restrict__ cursor) {
    __shared__ int lds[1024];
    int b = blockIdx.x, t = threadIdx.x;
    int prefix = 0;
    for (int k = 0; k < b; ++k) prefix += bsum[k];
    int i = b * 1024 + t;
    int v = (i < N_NODES) ? deg[i] : 0;
    lds[t] = v;
    __syncthreads();
    for (int off = 1; off < 1024; off <<= 1) {
        int x = (t >= off) ? lds[t - off] : 0;
        __syncthreads();
        lds[t] += x;
        __syncthreads();
    }
    int excl = prefix + lds[t] - v;
    if (i <= N_NODES) {
        rowptr[i] = excl;
        if (i < N_NODES) cursor[i] = excl;
    }
}

// XCD-sliced fill with NT streaming reads; col packed as ushort.
// blocks with blockIdx%8==s handle dst in [s*6250,(s+1)*6250)
__global__ __launch_bounds__(256) void k_fill(const int* __restrict__ src,
                                              const int* __restrict__ dst,
                                              int* __restrict__ cursor,
                                              unsigned short* __restrict__ col,
                                              int ne, int chunk) {
    int slice = blockIdx.x & (NSLICE - 1);
    int grp   = blockIdx.x >> 3;
    int lo = slice * SLICE_SZ;
    int hi = lo + SLICE_SZ;
    int start = grp * chunk;
    int end = start + chunk;
    if (end > ne) end = ne;
    for (int e = start + threadIdx.x; e < end; e += 256) {
        int d = __builtin_nontemporal_load(dst + e);
        int s = __builtin_nontemporal_load(src + e);
        if (d >= lo && d < hi) {
            int p = atomicAdd(&cursor[d], 1);
            col[p] = (unsigned short)s;
        }
    }
}

// ---------------------------------------------------------------------------
// GEMM: G(bf16) = X(f32) @ W, X: n x 128, W: 128 x 128 (row-major, W[k][c])
// block = 256 threads, 32 rows per block, 4x4 register tile
// ---------------------------------------------------------------------------
#define FMA4(a_, s_, v_) \
    do { (a_).x += (s_) * (v_).x; (a_).y += (s_) * (v_).y; \
         (a_).z += (s_) * (v_).z; (a_).w += (s_) * (v_).w; } while (0)

__global__ __launch_bounds__(256) void k_gemm128(const float* __restrict__ X,
                                                 const float* __restrict__ W,
                                                 unsigned short* __restrict__ G,
                                                 int nrows) {
    __shared__ float Ws[128 * 128];
    __shared__ float Xs[32 * 128];
    int t = threadIdx.x;
    int rowbase = blockIdx.x * 32;

    const float4* W4 = (const float4*)W;
    float4* Ws4 = (float4*)Ws;
#pragma unroll
    for (int i = 0; i < 16; ++i) Ws4[t + i * 256] = W4[t + i * 256];

    const float4* X4 = (const float4*)X;
    float4* Xs4 = (float4*)Xs;
#pragma unroll
    for (int i = 0; i < 4; ++i) {
        int idx = t + i * 256;            // float4 index in 32x32 tile
        int r = rowbase + (idx >> 5);
        Xs4[idx] = (r < nrows) ? X4[r * 32 + (idx & 31)] : make_float4(0.f, 0.f, 0.f, 0.f);
    }
    __syncthreads();

    int cg = t & 31;   // cols = cg*4 .. cg*4+3
    int rg = t >> 5;   // rows = rg*4 .. rg*4+3
    float4 acc[4];
#pragma unroll
    for (int r = 0; r < 4; ++r) acc[r] = make_float4(0.f, 0.f, 0.f, 0.f);

    for (int kk = 0; kk < 32; ++kk) {
        float4 x0 = Xs4[(rg * 4 + 0) * 32 + kk];
        float4 x1 = Xs4[(rg * 4 + 1) * 32 + kk];
        float4 x2 = Xs4[(rg * 4 + 2) * 32 + kk];
        float4 x3 = Xs4[(rg * 4 + 3) * 32 + kk];
        float4 w0 = Ws4[(kk * 4 + 0) * 32 + cg];
        float4 w1 = Ws4[(kk * 4 + 1) * 32 + cg];
        float4 w2 = Ws4[(kk * 4 + 2) * 32 + cg];
        float4 w3 = Ws4[(kk * 4 + 3) * 32 + cg];
        FMA4(acc[0], x0.x, w0); FMA4(acc[0], x0.y, w1); FMA4(acc[0], x0.z, w2); FMA4(acc[0], x0.w, w3);
        FMA4(acc[1], x1.x, w0); FMA4(acc[1], x1.y, w1); FMA4(acc[1], x1.z, w2); FMA4(acc[1], x1.w, w3);
        FMA4(acc[2], x2.x, w0); FMA4(acc[2], x2.y, w1); FMA4(acc[2], x2.z, w2); FMA4(acc[2], x2.w, w3);
        FMA4(acc[3], x3.x, w0); FMA4(acc[3], x3.y, w1); FMA4(acc[3], x3.z, w2); FMA4(acc[3], x3.w, w3);
    }

#pragma unroll
    for (int r = 0; r < 4; ++r) {
        int row = rowbase + rg * 4 + r;
        if (row < nrows) {
            ushort4 o;
            o.x = f2bf(acc[r].x); o.y = f2bf(acc[r].y);
            o.z = f2bf(acc[r].z); o.w = f2bf(acc[r].w);
            *(ushort4*)(G + (size_t)row * 128 + cg * 4) = o;
        }
    }
}

// ---------------------------------------------------------------------------
// Gather+bias+ReLU from bf16 g: out[v] = act(g[v] + sum_j g[col[j]] + b)
// one wave per node; lane owns 2 bf16 at d = lane*2 (one uint load)
// ---------------------------------------------------------------------------
__global__ __launch_bounds__(256) void k_gather128(const unsigned short* __restrict__ g,
                                                   const int* __restrict__ rowptr,
                                                   const unsigned short* __restrict__ col,
                                                   const float* __restrict__ bias,
                                                   float* __restrict__ out,
                                                   int do_relu) {
    int node = blockIdx.x * 4 + (threadIdx.x >> 6);
    if (node >= N_NODES) return;
    int lane = threadIdx.x & 63;
    const unsigned int* g2 = (const unsigned int*)g;

    float2 bb = ((const float2*)bias)[lane];
    unsigned int sv = g2[(size_t)node * 64 + lane];
    float2 a0 = make_float2(bb.x + __uint_as_float(sv << 16),
                            bb.y + __uint_as_float(sv & 0xffff0000u));
    float2 a1 = make_float2(0.f, 0.f);
    float2 a2 = make_float2(0.f, 0.f);
    float2 a3 = make_float2(0.f, 0.f);

    int s = rowptr[node], e = rowptr[node + 1];
    int j = s;
    for (; j + 3 < e; j += 4) {
        int u0 = col[j], u1 = col[j + 1], u2 = col[j + 2], u3 = col[j + 3];
        unsigned int v0 = g2[(size_t)u0 * 64 + lane];
        unsigned int v1 = g2[(size_t)u1 * 64 + lane];
        unsigned int v2 = g2[(size_t)u2 * 64 + lane];
        unsigned int v3 = g2[(size_t)u3 * 64 + lane];
        a0.x += __uint_as_float(v0 << 16); a0.y += __uint_as_float(v0 & 0xffff0000u);
        a1.x += __uint_as_float(v1 << 16); a1.y += __uint_as_float(v1 & 0xffff0000u);
        a2.x += __uint_as_float(v2 << 16); a2.y += __uint_as_float(v2 & 0xffff0000u);
        a3.x += __uint_as_float(v3 << 16); a3.y += __uint_as_float(v3 & 0xffff0000u);
    }
    for (; j < e; ++j) {
        int u = col[j];
        unsigned int v = g2[(size_t)u * 64 + lane];
        a0.x += __uint_as_float(v << 16); a0.y += __uint_as_float(v & 0xffff0000u);
    }
    float2 acc = make_float2(a0.x + a1.x + a2.x + a3.x, a0.y + a1.y + a2.y + a3.y);
    if (do_relu) { acc.x = fmaxf(acc.x, 0.f); acc.y = fmaxf(acc.y, 0.f); }
    ((float2*)out)[(size_t)node * 64 + lane] = acc;
}

// ---------------------------------------------------------------------------
// Final GEMM: Y = X @ W3, W3: 128 x 4.  4 threads per row, shfl reduce.
// ---------------------------------------------------------------------------
__global__ __launch_bounds__(256) void k_gemm_final(const float* __restrict__ X,
                                                    const float* __restrict__ W3,
                                                    float* __restrict__ Y, int nrows) {
    __shared__ float Ws[128 * 4];
    int t = threadIdx.x;
    if (t < 128) ((float4*)Ws)[t] = ((const float4*)W3)[t];
    __syncthreads();

    int idx = blockIdx.x * 256 + t;
    int row = idx >> 2;
    int q = idx & 3;
    if (row >= nrows) return;

    const float4* X4 = (const float4*)X;
    float acc[4] = {0.f, 0.f, 0.f, 0.f};
#pragma unroll
    for (int i = 0; i < 8; ++i) {
        float4 x = X4[row * 32 + q * 8 + i];
        int k = q * 32 + i * 4;
#pragma unroll
        for (int c = 0; c < 4; ++c) {
            acc[c] += x.x * Ws[(k + 0) * 4 + c] + x.y * Ws[(k + 1) * 4 + c]
                    + x.z * Ws[(k + 2) * 4 + c] + x.w * Ws[(k + 3) * 4 + c];
        }
    }
#pragma unroll
    for (int off = 1; off < 4; off <<= 1) {
#pragma unroll
        for (int c = 0; c < 4; ++c) acc[c] += __shfl_xor(acc[c], off, 64);
    }
    if (q == 0) ((float4*)Y)[row] = make_float4(acc[0], acc[1], acc[2], acc[3]);
}

// ---------------------------------------------------------------------------
// Final gather: out[v] = y[v] + sum_j y[col[j]] + b3   (4 floats per node)
// ---------------------------------------------------------------------------
__global__ __launch_bounds__(256) void k_gather4(const float* __restrict__ y,
                                                 const int* __restrict__ rowptr,
                                                 const unsigned short* __restrict__ col,
                                                 const float* __restrict__ b3,
                                                 float* __restrict__ out) {
    int v = blockIdx.x * 256 + threadIdx.x;
    if (v >= N_NODES) return;
    const float4* y4 = (const float4*)y;
    float4 acc = y4[v];
    float4 bb = *(const float4*)b3;
    acc.x += bb.x; acc.y += bb.y; acc.z += bb.z; acc.w += bb.w;
    int s = rowptr[v], e = rowptr[v + 1];
    for (int j = s; j < e; ++j) {
        float4 t = y4[col[j]];
        acc.x += t.x; acc.y += t.y; acc.z += t.z; acc.w += t.w;
    }
    ((float4*)out)[v] = acc;
}

// ---------------------------------------------------------------------------
extern "C" void kernel_launch(void* const* d_in, const int* in_sizes, int n_in,
                              void* d_out, int out_size, void* d_ws, size_t ws_size,
                              hipStream_t stream) {
    const float* feat = (const float*)d_in[0];
    const int*   src  = (const int*)d_in[1];
    const int*   dst  = (const int*)d_in[2];
    const float* W0 = (const float*)d_in[3];
    const float* b0 = (const float*)d_in[4];
    const float* W1 = (const float*)d_in[5];
    const float* b1 = (const float*)d_in[6];
    const float* W2 = (const float*)d_in[7];
    const float* b2 = (const float*)d_in[8];
    const float* W3 = (const float*)d_in[9];
    const float* b3 = (const float*)d_in[10];

    const int n  = N_NODES;
    const int ne = in_sizes[1];

    // workspace layout (256B aligned)
    char* p = (char*)d_ws;
    auto alloc = [&](size_t bytes) {
        char* r = p;
        p += (bytes + 255) & ~(size_t)255;
        return r;
    };
    int*   rowptr = (int*)alloc((n + 1) * sizeof(int));
    int*   deg    = (int*)alloc(n * sizeof(int));
    int*   cursor = (int*)alloc(n * sizeof(int));
    int*   bsum   = (int*)alloc(64 * sizeof(int));
    unsigned short* col = (unsigned short*)alloc(ne * sizeof(unsigned short));
    unsigned short* g = (unsigned short*)alloc((size_t)n * 128 * sizeof(unsigned short));
    float* hA     = (float*)alloc((size_t)n * 128 * sizeof(float));
    float* hB     = (float*)alloc((size_t)n * 128 * sizeof(float));
    float* y      = (float*)alloc((size_t)n * 4 * sizeof(float));
    float* outf   = (float*)d_out;

    int eb = (ne + 255) / 256;
    int gemmb = (n + 31) / 32;
    int gathb = (n + 3) / 4;
    int nb256 = (n + 255) / 256;
    int scanb = (n + 1023) / 1024;           // 49

    // sliced fill config: 128 blocks per slice
    const int BPS = 128;
    int chunk = (ne + BPS - 1) / BPS;

    // --- CSR build ---
    hipMemsetAsync(deg, 0, n * sizeof(int), stream);
    k_hist<<<eb, 256, 0, stream>>>(dst, deg, ne);
    k_blocksum<<<scanb, 1024, 0, stream>>>(deg, bsum);
    k_scan2<<<scanb, 1024, 0, stream>>>(deg, bsum, rowptr, cursor);
    k_fill<<<NSLICE * BPS, 256, 0, stream>>>(src, dst, cursor, col, ne, chunk);

    // --- layer 0 ---
    k_gemm128<<<gemmb, 256, 0, stream>>>(feat, W0, g, n);
    k_gather128<<<gathb, 256, 0, stream>>>(g, rowptr, col, b0, hA, 1);
    // --- layer 1 ---
    k_gemm128<<<gemmb, 256, 0, stream>>>(hA, W1, g, n);
    k_gather128<<<gathb, 256, 0, stream>>>(g, rowptr, col, b1, hB, 1);
    // --- layer 2 ---
    k_gemm128<<<gemmb, 256, 0, stream>>>(hB, W2, g, n);
    k_gather128<<<gathb, 256, 0, stream>>>(g, rowptr, col, b2, hA, 1);
    // --- layer 3 (output dim 4) ---
    k_gemm_final<<<(n * 4 + 255) / 256, 256, 0, stream>>>(hA, W3, y, n);
    k_gather4<<<nb256, 256, 0, stream>>>(y, rowptr, col, b3, outf);
}

// Round 17
// 514.555 us; speedup vs baseline: 1.5591x; 1.0361x over previous
//
#include <hip/hip_runtime.h>
#include <hip/hip_bf16.h>

#define N_NODES 50000
#define NSLICE 8
#define SLICE_SZ 6250   // N_NODES / NSLICE exactly

typedef int int4v __attribute__((ext_vector_type(4)));

// ---------------------------------------------------------------------------
// helpers
// ---------------------------------------------------------------------------
__device__ __forceinline__ unsigned short f2bf(float f) {
    unsigned int u = __float_as_uint(f);
    unsigned int r = (u + 0x7fffu + ((u >> 16) & 1u)) >> 16;   // RNE
    return (unsigned short)r;
}

// ---------------------------------------------------------------------------
// CSR build kernels
// ---------------------------------------------------------------------------
// 4 edges per thread via int4v
__global__ void k_hist(const int* __restrict__ dst, int* __restrict__ deg, int ne) {
    int g = blockIdx.x * 256 + threadIdx.x;
    int e = g * 4;
    if (e + 3 < ne) {
        int4v d = __builtin_nontemporal_load((const int4v*)(dst + e));
        atomicAdd(&deg[d.x], 1);
        atomicAdd(&deg[d.y], 1);
        atomicAdd(&deg[d.z], 1);
        atomicAdd(&deg[d.w], 1);
    } else if (e < ne) {
        for (int k = 0; k < 4 && e + k < ne; ++k) atomicAdd(&deg[dst[e + k]], 1);
    }
}

// 49 blocks x 1024: per-block sum of deg
__global__ __launch_bounds__(1024) void k_blocksum(const int* __restrict__ deg,
                                                   int* __restrict__ bsum) {
    int i = blockIdx.x * 1024 + threadIdx.x;
    int v = (i < N_NODES) ? deg[i] : 0;
#pragma unroll
    for (int off = 32; off >= 1; off >>= 1) v += __shfl_down(v, off, 64);
    __shared__ int ws[16];
    if ((threadIdx.x & 63) == 0) ws[threadIdx.x >> 6] = v;
    __syncthreads();
    if (threadIdx.x < 16) {
        int s = ws[threadIdx.x];
#pragma unroll
        for (int off = 8; off >= 1; off >>= 1) s += __shfl_down(s, off, 16);
        if (threadIdx.x == 0) bsum[blockIdx.x] = s;
    }
}

// 49 blocks x 1024: local scan + block prefix -> rowptr, cursor
__global__ __launch_bounds__(1024) void k_scan2(const int* __restrict__ deg,
                                                const int* __restrict__ bsum,
                                                int* __restrict__ rowptr,
                                                int* __restrict__ cursor) {
    __shared__ int lds[1024];
    int b = blockIdx.x, t = threadIdx.x;
    int prefix = 0;
    for (int k = 0; k < b; ++k) prefix += bsum[k];
    int i = b * 1024 + t;
    int v = (i < N_NODES) ? deg[i] : 0;
    lds[t] = v;
    __syncthreads();
    for (int off = 1; off < 1024; off <<= 1) {
        int x = (t >= off) ? lds[t - off] : 0;
        __syncthreads();
        lds[t] += x;
        __syncthreads();
    }
    int excl = prefix + lds[t] - v;
    if (i <= N_NODES) {
        rowptr[i] = excl;
        if (i < N_NODES) cursor[i] = excl;
    }
}

// XCD-sliced fill, 4 edges/thread int4v; src loaded only on slice match.
// blocks with blockIdx%8==s handle dst in [s*6250,(s+1)*6250)
__global__ __launch_bounds__(256) void k_fill(const int* __restrict__ src,
                                              const int* __restrict__ dst,
                                              int* __restrict__ cursor,
                                              unsigned short* __restrict__ col,
                                              int ne, int ng4, int chunk4) {
    int slice = blockIdx.x & (NSLICE - 1);
    int grp   = blockIdx.x >> 3;
    int lo = slice * SLICE_SZ;
    int hi = lo + SLICE_SZ;
    int g0 = grp * chunk4;
    int g1 = g0 + chunk4;
    if (g1 > ng4) g1 = ng4;
    for (int g = g0 + threadIdx.x; g < g1; g += 256) {
        int e = g * 4;
        if (e + 3 < ne) {
            int4v d = __builtin_nontemporal_load((const int4v*)(dst + e));
            bool m0 = (d.x >= lo) && (d.x < hi);
            bool m1 = (d.y >= lo) && (d.y < hi);
            bool m2 = (d.z >= lo) && (d.z < hi);
            bool m3 = (d.w >= lo) && (d.w < hi);
            if (m0 | m1 | m2 | m3) {
                int4v s = __builtin_nontemporal_load((const int4v*)(src + e));
                if (m0) { int p = atomicAdd(&cursor[d.x], 1); col[p] = (unsigned short)s.x; }
                if (m1) { int p = atomicAdd(&cursor[d.y], 1); col[p] = (unsigned short)s.y; }
                if (m2) { int p = atomicAdd(&cursor[d.z], 1); col[p] = (unsigned short)s.z; }
                if (m3) { int p = atomicAdd(&cursor[d.w], 1); col[p] = (unsigned short)s.w; }
            }
        } else {
            for (int k = 0; k < 4 && e + k < ne; ++k) {
                int dd = dst[e + k];
                if (dd >= lo && dd < hi) {
                    int ss = src[e + k];
                    int p = atomicAdd(&cursor[dd], 1);
                    col[p] = (unsigned short)ss;
                }
            }
        }
    }
}

// ---------------------------------------------------------------------------
// GEMM: G(bf16) = X(f32) @ W, X: n x 128, W: 128 x 128 (row-major, W[k][c])
// block = 256 threads, 32 rows per block, 4x4 register tile
// ---------------------------------------------------------------------------
#define FMA4(a_, s_, v_) \
    do { (a_).x += (s_) * (v_).x; (a_).y += (s_) * (v_).y; \
         (a_).z += (s_) * (v_).z; (a_).w += (s_) * (v_).w; } while (0)

__global__ __launch_bounds__(256) void k_gemm128(const float* __restrict__ X,
                                                 const float* __restrict__ W,
                                                 unsigned short* __restrict__ G,
                                                 int nrows) {
    __shared__ float Ws[128 * 128];
    __shared__ float Xs[32 * 128];
    int t = threadIdx.x;
    int rowbase = blockIdx.x * 32;

    const float4* W4 = (const float4*)W;
    float4* Ws4 = (float4*)Ws;
#pragma unroll
    for (int i = 0; i < 16; ++i) Ws4[t + i * 256] = W4[t + i * 256];

    const float4* X4 = (const float4*)X;
    float4* Xs4 = (float4*)Xs;
#pragma unroll
    for (int i = 0; i < 4; ++i) {
        int idx = t + i * 256;            // float4 index in 32x32 tile
        int r = rowbase + (idx >> 5);
        Xs4[idx] = (r < nrows) ? X4[r * 32 + (idx & 31)] : make_float4(0.f, 0.f, 0.f, 0.f);
    }
    __syncthreads();

    int cg = t & 31;   // cols = cg*4 .. cg*4+3
    int rg = t >> 5;   // rows = rg*4 .. rg*4+3
    float4 acc[4];
#pragma unroll
    for (int r = 0; r < 4; ++r) acc[r] = make_float4(0.f, 0.f, 0.f, 0.f);

    for (int kk = 0; kk < 32; ++kk) {
        float4 x0 = Xs4[(rg * 4 + 0) * 32 + kk];
        float4 x1 = Xs4[(rg * 4 + 1) * 32 + kk];
        float4 x2 = Xs4[(rg * 4 + 2) * 32 + kk];
        float4 x3 = Xs4[(rg * 4 + 3) * 32 + kk];
        float4 w0 = Ws4[(kk * 4 + 0) * 32 + cg];
        float4 w1 = Ws4[(kk * 4 + 1) * 32 + cg];
        float4 w2 = Ws4[(kk * 4 + 2) * 32 + cg];
        float4 w3 = Ws4[(kk * 4 + 3) * 32 + cg];
        FMA4(acc[0], x0.x, w0); FMA4(acc[0], x0.y, w1); FMA4(acc[0], x0.z, w2); FMA4(acc[0], x0.w, w3);
        FMA4(acc[1], x1.x, w0); FMA4(acc[1], x1.y, w1); FMA4(acc[1], x1.z, w2); FMA4(acc[1], x1.w, w3);
        FMA4(acc[2], x2.x, w0); FMA4(acc[2], x2.y, w1); FMA4(acc[2], x2.z, w2); FMA4(acc[2], x2.w, w3);
        FMA4(acc[3], x3.x, w0); FMA4(acc[3], x3.y, w1); FMA4(acc[3], x3.z, w2); FMA4(acc[3], x3.w, w3);
    }

#pragma unroll
    for (int r = 0; r < 4; ++r) {
        int row = rowbase + rg * 4 + r;
        if (row < nrows) {
            ushort4 o;
            o.x = f2bf(acc[r].x); o.y = f2bf(acc[r].y);
            o.z = f2bf(acc[r].z); o.w = f2bf(acc[r].w);
            *(ushort4*)(G + (size_t)row * 128 + cg * 4) = o;
        }
    }
}

// ---------------------------------------------------------------------------
// Gather+bias+ReLU from bf16 g, split-wave: halves of the wave process two
// independent neighbor streams; lane owns 4 bf16 (uint2, 8B) of the row.
// ---------------------------------------------------------------------------
#define ACC4(a_, v_) \
    do { (a_).x += __uint_as_float((v_).x << 16); \
         (a_).y += __uint_as_float((v_).x & 0xffff0000u); \
         (a_).z += __uint_as_float((v_).y << 16); \
         (a_).w += __uint_as_float((v_).y & 0xffff0000u); } while (0)

__global__ __launch_bounds__(256) void k_gather128(const unsigned short* __restrict__ g,
                                                   const int* __restrict__ rowptr,
                                                   const unsigned short* __restrict__ col,
                                                   const float* __restrict__ bias,
                                                   float* __restrict__ out,
                                                   int do_relu) {
    int node = blockIdx.x * 4 + (threadIdx.x >> 6);
    if (node >= N_NODES) return;
    int lane = threadIdx.x & 63;
    int li = lane & 31;          // uint2 index within 256B row (32 per row)
    int half = lane >> 5;        // neighbor stream id
    const uint2* g2 = (const uint2*)g;

    float4 a0 = make_float4(0.f, 0.f, 0.f, 0.f);
    float4 a1 = make_float4(0.f, 0.f, 0.f, 0.f);
    float4 a2 = make_float4(0.f, 0.f, 0.f, 0.f);
    float4 a3 = make_float4(0.f, 0.f, 0.f, 0.f);

    int s = rowptr[node], e = rowptr[node + 1];
    int j = s + half;            // this half's stream: j, j+2, j+4, ...
    for (; j + 6 < e; j += 8) {  // 4 neighbors per half in flight (8 per wave)
        int u0 = col[j], u1 = col[j + 2], u2 = col[j + 4], u3 = col[j + 6];
        uint2 v0 = g2[(size_t)u0 * 32 + li];
        uint2 v1 = g2[(size_t)u1 * 32 + li];
        uint2 v2 = g2[(size_t)u2 * 32 + li];
        uint2 v3 = g2[(size_t)u3 * 32 + li];
        ACC4(a0, v0); ACC4(a1, v1); ACC4(a2, v2); ACC4(a3, v3);
    }
    for (; j < e; j += 2) {
        int u = col[j];
        uint2 v = g2[(size_t)u * 32 + li];
        ACC4(a0, v);
    }
    float4 acc = make_float4(a0.x + a1.x + a2.x + a3.x,
                             a0.y + a1.y + a2.y + a3.y,
                             a0.z + a1.z + a2.z + a3.z,
                             a0.w + a1.w + a2.w + a3.w);
    // combine the two halves (lane l <-> l^32)
    acc.x += __shfl_xor(acc.x, 32, 64);
    acc.y += __shfl_xor(acc.y, 32, 64);
    acc.z += __shfl_xor(acc.z, 32, 64);
    acc.w += __shfl_xor(acc.w, 32, 64);

    if (half == 0) {
        uint2 sv = g2[(size_t)node * 32 + li];
        float4 bb = ((const float4*)bias)[li];
        acc.x += bb.x + __uint_as_float(sv.x << 16);
        acc.y += bb.y + __uint_as_float(sv.x & 0xffff0000u);
        acc.z += bb.z + __uint_as_float(sv.y << 16);
        acc.w += bb.w + __uint_as_float(sv.y & 0xffff0000u);
        if (do_relu) {
            acc.x = fmaxf(acc.x, 0.f); acc.y = fmaxf(acc.y, 0.f);
            acc.z = fmaxf(acc.z, 0.f); acc.w = fmaxf(acc.w, 0.f);
        }
        ((float4*)out)[(size_t)node * 32 + li] = acc;
    }
}

// ---------------------------------------------------------------------------
// Final GEMM: Y = X @ W3, W3: 128 x 4.  4 threads per row, shfl reduce.
// ---------------------------------------------------------------------------
__global__ __launch_bounds__(256) void k_gemm_final(const float* __restrict__ X,
                                                    const float* __restrict__ W3,
                                                    float* __restrict__ Y, int nrows) {
    __shared__ float Ws[128 * 4];
    int t = threadIdx.x;
    if (t < 128) ((float4*)Ws)[t] = ((const float4*)W3)[t];
    __syncthreads();

    int idx = blockIdx.x * 256 + t;
    int row = idx >> 2;
    int q = idx & 3;
    if (row >= nrows) return;

    const float4* X4 = (const float4*)X;
    float acc[4] = {0.f, 0.f, 0.f, 0.f};
#pragma unroll
    for (int i = 0; i < 8; ++i) {
        float4 x = X4[row * 32 + q * 8 + i];
        int k = q * 32 + i * 4;
#pragma unroll
        for (int c = 0; c < 4; ++c) {
            acc[c] += x.x * Ws[(k + 0) * 4 + c] + x.y * Ws[(k + 1) * 4 + c]
                    + x.z * Ws[(k + 2) * 4 + c] + x.w * Ws[(k + 3) * 4 + c];
        }
    }
#pragma unroll
    for (int off = 1; off < 4; off <<= 1) {
#pragma unroll
        for (int c = 0; c < 4; ++c) acc[c] += __shfl_xor(acc[c], off, 64);
    }
    if (q == 0) ((float4*)Y)[row] = make_float4(acc[0], acc[1], acc[2], acc[3]);
}

// ---------------------------------------------------------------------------
// Final gather: out[v] = y[v] + sum_j y[col[j]] + b3   (4 floats per node)
// ---------------------------------------------------------------------------
__global__ __launch_bounds__(256) void k_gather4(const float* __restrict__ y,
                                                 const int* __restrict__ rowptr,
                                                 const unsigned short* __restrict__ col,
                                                 const float* __restrict__ b3,
                                                 float* __restrict__ out) {
    int v = blockIdx.x * 256 + threadIdx.x;
    if (v >= N_NODES) return;
    const float4* y4 = (const float4*)y;
    float4 acc = y4[v];
    float4 bb = *(const float4*)b3;
    acc.x += bb.x; acc.y += bb.y; acc.z += bb.z; acc.w += bb.w;
    int s = rowptr[v], e = rowptr[v + 1];
    for (int j = s; j < e; ++j) {
        float4 t = y4[col[j]];
        acc.x += t.x; acc.y += t.y; acc.z += t.z; acc.w += t.w;
    }
    ((float4*)out)[v] = acc;
}

// ---------------------------------------------------------------------------
extern "C" void kernel_launch(void* const* d_in, const int* in_sizes, int n_in,
                              void* d_out, int out_size, void* d_ws, size_t ws_size,
                              hipStream_t stream) {
    const float* feat = (const float*)d_in[0];
    const int*   src  = (const int*)d_in[1];
    const int*   dst  = (const int*)d_in[2];
    const float* W0 = (const float*)d_in[3];
    const float* b0 = (const float*)d_in[4];
    const float* W1 = (const float*)d_in[5];
    const float* b1 = (const float*)d_in[6];
    const float* W2 = (const float*)d_in[7];
    const float* b2 = (const float*)d_in[8];
    const float* W3 = (const float*)d_in[9];
    const float* b3 = (const float*)d_in[10];

    const int n  = N_NODES;
    const int ne = in_sizes[1];

    // workspace layout (256B aligned)
    char* p = (char*)d_ws;
    auto alloc = [&](size_t bytes) {
        char* r = p;
        p += (bytes + 255) & ~(size_t)255;
        return r;
    };
    int*   rowptr = (int*)alloc((n + 1) * sizeof(int));
    int*   deg    = (int*)alloc(n * sizeof(int));
    int*   cursor = (int*)alloc(n * sizeof(int));
    int*   bsum   = (int*)alloc(64 * sizeof(int));
    unsigned short* col = (unsigned short*)alloc(ne * sizeof(unsigned short));
    unsigned short* g = (unsigned short*)alloc((size_t)n * 128 * sizeof(unsigned short));
    float* hA     = (float*)alloc((size_t)n * 128 * sizeof(float));
    float* hB     = (float*)alloc((size_t)n * 128 * sizeof(float));
    float* y      = (float*)alloc((size_t)n * 4 * sizeof(float));
    float* outf   = (float*)d_out;

    int gemmb = (n + 31) / 32;
    int gathb = (n + 3) / 4;
    int nb256 = (n + 255) / 256;
    int scanb = (n + 1023) / 1024;           // 49

    int ng4 = (ne + 3) / 4;                  // int4 edge groups
    int histb = (ng4 + 255) / 256;

    // sliced fill config: 128 blocks per slice
    const int BPS = 128;
    int chunk4 = (ng4 + BPS - 1) / BPS;

    // --- CSR build ---
    hipMemsetAsync(deg, 0, n * sizeof(int), stream);
    k_hist<<<histb, 256, 0, stream>>>(dst, deg, ne);
    k_blocksum<<<scanb, 1024, 0, stream>>>(deg, bsum);
    k_scan2<<<scanb, 1024, 0, stream>>>(deg, bsum, rowptr, cursor);
    k_fill<<<NSLICE * BPS, 256, 0, stream>>>(src, dst, cursor, col, ne, ng4, chunk4);

    // --- layer 0 ---
    k_gemm128<<<gemmb, 256, 0, stream>>>(feat, W0, g, n);
    k_gather128<<<gathb, 256, 0, stream>>>(g, rowptr, col, b0, hA, 1);
    // --- layer 1 ---
    k_gemm128<<<gemmb, 256, 0, stream>>>(hA, W1, g, n);
    k_gather128<<<gathb, 256, 0, stream>>>(g, rowptr, col, b1, hB, 1);
    // --- layer 2 ---
    k_gemm128<<<gemmb, 256, 0, stream>>>(hB, W2, g, n);
    k_gather128<<<gathb, 256, 0, stream>>>(g, rowptr, col, b2, hA, 1);
    // --- layer 3 (output dim 4) ---
    k_gemm_final<<<(n * 4 + 255) / 256, 256, 0, stream>>>(hA, W3, y, n);
    k_gather4<<<nb256, 256, 0, stream>>>(y, rowptr, col, b3, outf);
}